// Round 10
// baseline (16484.554 us; speedup 1.0000x reference)
//
#include <hip/hip_runtime.h>

// samx_qkv_1bit R10: R9 design with writelane replaced by predicated
// register update (ROCm clang on gfx950 lacks __builtin_amdgcn_writelane;
// readlane exists and is verified since R2).
// Design: R7 split-array state (exactly 40960 B LDS -> 4 blocks/CU) +
// suffix-path chain in WAVE REGISTERS. Key side does zero pointer-chasing:
//   sweep 1 finds the breaker via chunked batch loads of tk[chain[t]]
//   (chunk 0 hoisted above the query walks to hide latency); prefix tk:=j,
//   clone, redirect stores are blind; new chain = [j]+dedup(images)+[root];
//   endpos propagation = blind rl:=i stamps of the new chain.
// All 64 lanes run the loop redundantly (uniform control flow); LDS/global
// stores are lane-0-predicated in 3 regions/step. cset: lane==t&63 cndmask.
// Chain cap 256 (random chains ~25); overflow -> reference-exact serial step.

#define NSTATES 4096
#define TLEN 2048
#define CAP 256

__global__ __launch_bounds__(64)
void samx_main(const float* __restrict__ q,
               const float* __restrict__ k,
               unsigned* __restrict__ outpos,
               int T, int C) {
  __shared__ unsigned short tr0[NSTATES];
  __shared__ unsigned short tr1[NSTATES];
  __shared__ unsigned       flml[NSTATES];  // fl[15:0] (0xFFFF=-1), ml[31:16]
  __shared__ unsigned short rl[NSTATES];    // last end pos, 0xFFFF = -1

  const int row = blockIdx.x;
  const int b = row / C;
  const int c = row - b * C;
  const int lane = threadIdx.x;

  for (int s = lane; s < NSTATES; s += 64) {
    tr0[s] = 0xFFFFu; tr1[s] = 0xFFFFu;
    flml[s] = 0x0000FFFFu; rl[s] = 0xFFFFu;
  }

  const size_t rowbase = (size_t)b * (size_t)T * (size_t)C + (size_t)c;
  const float* qr = q + rowbase;
  const float* kr = k + rowbase;
  unsigned* outr = outpos + rowbase;

  // Pre-binarize: lane L holds bits t = 32L..32L+31 of q and k.
  unsigned qw = 0u, kw = 0u;
  {
    const int t0 = lane * 32;
#pragma unroll 8
    for (int jj = 0; jj < 32; ++jj) {
      const int t = t0 + jj;
      if (qr[(size_t)t * C] > 0.0f) qw |= (1u << jj);
      if (kr[(size_t)t * C] > 0.0f) kw |= (1u << jj);
    }
  }
  __syncthreads();
  // NOTE: all 64 lanes continue; control flow below is wave-uniform.

  // ---- chain storage: 8 u32 slots = 2 banks x 4; entry t of bank bk lives
  // in slot bk*4+(t>>6), lane t&63. read: readlane; write: predicated
  // per-lane update (v_cmp+v_cndmask) — t and v are wave-uniform. ----
  unsigned c0 = 0, c1 = 0, c2 = 0, c3 = 0, c4 = 0, c5 = 0, c6 = 0, c7 = 0;
  auto cget = [&](int bk, int t) -> int {
    const int ln = t & 63;
    switch ((bk << 2) | (t >> 6)) {
      case 0:  return __builtin_amdgcn_readlane((int)c0, ln);
      case 1:  return __builtin_amdgcn_readlane((int)c1, ln);
      case 2:  return __builtin_amdgcn_readlane((int)c2, ln);
      case 3:  return __builtin_amdgcn_readlane((int)c3, ln);
      case 4:  return __builtin_amdgcn_readlane((int)c4, ln);
      case 5:  return __builtin_amdgcn_readlane((int)c5, ln);
      case 6:  return __builtin_amdgcn_readlane((int)c6, ln);
      default: return __builtin_amdgcn_readlane((int)c7, ln);
    }
  };
  auto cset = [&](int bk, int t, int v) {
    const bool own = (lane == (t & 63));
    switch ((bk << 2) | (t >> 6)) {
      case 0:  c0 = own ? (unsigned)v : c0; break;
      case 1:  c1 = own ? (unsigned)v : c1; break;
      case 2:  c2 = own ? (unsigned)v : c2; break;
      case 3:  c3 = own ? (unsigned)v : c3; break;
      case 4:  c4 = own ? (unsigned)v : c4; break;
      case 5:  c5 = own ? (unsigned)v : c5; break;
      case 6:  c6 = own ? (unsigned)v : c6; break;
      default: c7 = own ? (unsigned)v : c7; break;
    }
  };

  cset(0, 0, 0);          // initial chain = [root]
  int len = 1;
  bool trunc = false;

  int mlg = 0;  // ml of chain[0] (ml of an existing state never changes)
  int u = 1;    // next free state id
  int w = 0;    // query-match state
  int h = 0;    // query-match length

  for (int i = 0; i < T; ++i) {
    const int bank = i & 1, nbank = bank ^ 1;
    const unsigned qwi = (unsigned)__builtin_amdgcn_readlane((int)qw, i >> 5);
    const unsigned kwi = (unsigned)__builtin_amdgcn_readlane((int)kw, i >> 5);
    const int qs = (int)((qwi >> (i & 31)) & 1u);
    const int ks = (int)((kwi >> (i & 31)) & 1u);
    unsigned short* tq = qs ? tr1 : tr0;
    unsigned short* tk = ks ? tr1 : tr0;

    // ---- prefetch chunk 0 of key sweep (latency hides under query walks) ----
    int ids0[8], tvs0[8];
    if (!trunc) {
#pragma unroll
      for (int a = 0; a < 8; ++a) {
        int tt = (a < len) ? a : (len - 1);
        ids0[a] = cget(bank, tt);
      }
#pragma unroll
      for (int a = 0; a < 8; ++a) tvs0[a] = (int)(short)tk[ids0[a]];
    }

    // ================= QUERY (verbatim R7) =================
    int p = w, x = h;
    int pnew, xnew;
    for (;;) {
      if (p == -1) { pnew = 0; xnew = 0; break; }
      const int t = (int)(short)tq[p];
      const unsigned fm = flml[p];
      if (t != -1) { pnew = t; xnew = x + 1; break; }
      const int mp = (int)(fm >> 16);
      if (x > mp) x = mp;
      p = (int)(short)(fm & 0xFFFFu);
    }
    p = pnew; x = xnew;

    int vst = p;
    unsigned fmv = flml[vst];
    for (;;) {
      const int fv = (int)(short)(fmv & 0xFFFFu);
      if (fv == -1) break;
      const unsigned fmf = flml[fv];
      if ((int)(fmf >> 16) < x) break;
      vst = fv; fmv = fmf;
    }
    int rv = -1;
    for (;;) {
      if (vst == -1) { rv = -1; break; }
      const unsigned fm2 = flml[vst];
      const int r2 = (int)(short)rl[vst];
      if ((int)(fm2 >> 16) > 0 && r2 >= 0) { rv = r2; break; }
      vst = (int)(short)(fm2 & 0xFFFFu);
    }
    w = p; h = x;

    // ================= KEY SIDE =================
    const int j = u++;
    const int mlj = mlg + 1;

    if (!trunc) {
      // ---- sweep 1: find breaker (chunked batch loads) ----
      int t2 = -1, d = -1, idt2 = -1;
      {
        int ids[8], tvs[8];
#pragma unroll
        for (int a = 0; a < 8; ++a) { ids[a] = ids0[a]; tvs[a] = tvs0[a]; }
        int t = 0;
        for (;;) {
#pragma unroll
          for (int a = 0; a < 8; ++a) {
            if (t + a < len && t2 < 0 && tvs[a] != -1) {
              t2 = t + a; d = tvs[a]; idt2 = ids[a];
            }
          }
          t += 8;
          if (t2 >= 0 || t >= len) break;
#pragma unroll
          for (int a = 0; a < 8; ++a) {
            int tt = (t + a < len) ? (t + a) : (len - 1);
            ids[a] = cget(bank, tt);
          }
#pragma unroll
          for (int a = 0; a < 8; ++a) tvs[a] = (int)(short)tk[ids[a]];
        }
      }

      // ---- region 1: prefix stores tk[chain[t]] = j, t < pend ----
      const int pend = (t2 >= 0) ? t2 : len;
      if (lane == 0) {
        for (int t = 0; t < pend; ++t)
          tk[cget(bank, t)] = (unsigned short)j;
      }

      // ---- clone decision (loads AFTER prefix stores: reference order) ----
      int flj = 0, bb = -1, mlp = 0;
      unsigned fmd = 0; int dtr0 = 0, dtr1 = 0, drl = 0;
      if (d != -1) {
        mlp = (int)(flml[idt2] >> 16);
        fmd = flml[d];
        const int mld = (int)(fmd >> 16);
        if (mlp + 1 == mld) {
          flj = d;
        } else {
          bb = u++;
          dtr0 = (int)tr0[d]; dtr1 = (int)tr1[d]; drl = (int)rl[d];
          flj = bb;
        }
      }

      // ---- region 2: clone stores + j's record ----
      if (lane == 0) {
        if (bb >= 0) {
          tr0[bb] = (unsigned short)dtr0;
          tr1[bb] = (unsigned short)dtr1;
          rl[bb]  = (unsigned short)drl;
          flml[bb] = (fmd & 0xFFFFu) | ((unsigned)(mlp + 1) << 16);
          flml[d]  = (fmd & 0xFFFF0000u) | (unsigned)bb;
        }
        flml[j] = (unsigned)(flj & 0xFFFF) | ((unsigned)mlj << 16);
        rl[j] = (unsigned short)i;
      }

      // ---- build new chain = [j] + dedup(images) + [root] ----
      int nc = 1;
      cset(nbank, 0, j);
      int rcount = 0, prev = j, lastStored = j;
      bool newtrunc = false;
      if (d != -1) {
        const int img0 = (bb >= 0) ? bb : d;
        cset(nbank, 1, img0); nc = 2; prev = img0; lastStored = img0;
        if (bb >= 0) rcount = 1;
        bool redir = (bb >= 0);
        int t = t2 + 1;
        while (t < len) {
          int ids[8], tvs[8];
#pragma unroll
          for (int a = 0; a < 8; ++a) {
            int tt = (t + a < len) ? (t + a) : (len - 1);
            ids[a] = cget(bank, tt);
          }
#pragma unroll
          for (int a = 0; a < 8; ++a) tvs[a] = (int)(short)tk[ids[a]];
#pragma unroll
          for (int a = 0; a < 8; ++a) {
            if (t + a < len) {
              const int tv = tvs[a];
              int img;
              if (redir && tv == d) { img = bb; ++rcount; }
              else { redir = false; img = tv; }
              if (img != prev) {
                prev = img;
                if (nc < CAP) { cset(nbank, nc, img); lastStored = img; ++nc; }
                else newtrunc = true;
              }
            }
          }
          t += 8;
        }
        if (prev != 0) {  // terminate with root
          if (nc < CAP) { cset(nbank, nc, 0); lastStored = 0; ++nc; }
          else newtrunc = true;
        }
      } else {
        cset(nbank, 1, 0); nc = 2; lastStored = 0;
      }

      // ---- region 3: redirect stores + rl stamps + output ----
      if (lane == 0) {
        for (int t = t2; t < t2 + rcount; ++t)
          tk[cget(bank, t)] = (unsigned short)bb;
        for (int t = 1; t < nc; ++t)
          rl[cget(nbank, t)] = (unsigned short)i;
        if (newtrunc) {  // stamp the unstored suffix-path tail serially
          int vp = (int)(short)(flml[lastStored] & 0xFFFFu);
          while (vp != -1) {
            rl[vp] = (unsigned short)i;
            vp = (int)(short)(flml[vp] & 0xFFFFu);
          }
        }
        outr[(size_t)i * C] = (unsigned)(rv + 1);
      }

      len = nc; trunc = newtrunc; mlg = mlj;
    } else {
      // ======= COLD fallback: reference-exact serial step (R7 code) =======
      const int g0 = cget(bank, 0);
      int pcur = g0, d = -1, idbrk = -1;
      for (;;) {
        if (pcur == -1) break;
        const int tv = (int)(short)tk[pcur];
        const unsigned fm = flml[pcur];
        if (tv != -1) { d = tv; idbrk = pcur; break; }
        if (lane == 0) tk[pcur] = (unsigned short)j;
        pcur = (int)(short)(fm & 0xFFFFu);
      }
      int flj = 0;
      if (d != -1) {
        const int mlp = (int)(flml[idbrk] >> 16);
        const unsigned fmd = flml[d];
        const int mld = (int)(fmd >> 16);
        if (mlp + 1 == mld) {
          flj = d;
        } else {
          const int bb = u++;
          const int dtr0 = (int)tr0[d], dtr1 = (int)tr1[d], drl = (int)rl[d];
          if (lane == 0) {
            tr0[bb] = (unsigned short)dtr0;
            tr1[bb] = (unsigned short)dtr1;
            rl[bb]  = (unsigned short)drl;
            flml[bb] = (fmd & 0xFFFFu) | ((unsigned)(mlp + 1) << 16);
            flml[d]  = (fmd & 0xFFFF0000u) | (unsigned)bb;
          }
          flj = bb;
          int p3 = idbrk;
          for (;;) {
            if (p3 == -1) break;
            const int tv3 = (int)(short)tk[p3];
            const unsigned fm3 = flml[p3];
            if (tv3 != d) break;
            if (lane == 0) tk[p3] = (unsigned short)bb;
            p3 = (int)(short)(fm3 & 0xFFFFu);
          }
        }
      }
      if (lane == 0)
        flml[j] = (unsigned)(flj & 0xFFFF) | ((unsigned)mlj << 16);
      // rebuild chain from j while stamping rl = i (full propagation)
      int vp = j, ncs = 0;
      bool tr2 = false;
      for (;;) {
        if (vp == -1) break;
        if (ncs < CAP) { cset(nbank, ncs, vp); ++ncs; }
        else tr2 = true;
        if (lane == 0) rl[vp] = (unsigned short)i;
        vp = (int)(short)(flml[vp] & 0xFFFFu);
      }
      if (lane == 0) outr[(size_t)i * C] = (unsigned)(rv + 1);
      len = ncs; trunc = tr2; mlg = mlj;
    }
  }
}

// Fully parallel epilogue: vidx (u32, = r+1, 0 = no match) -> sign*e.
__global__ __launch_bounds__(256)
void samx_epilogue(const float* __restrict__ v,
                   const float* __restrict__ e,
                   unsigned* __restrict__ out,
                   int T, int C, int total) {
  const int idx = blockIdx.x * 256 + threadIdx.x;
  if (idx >= total) return;
  const unsigned vidx = out[idx];
  const int c = idx % C;
  const int bi = idx / C;
  const int b = bi / T;
  const float ev = e[c];
  float val = -ev;  // y=0
  if (vidx != 0u) {
    if (v[((size_t)b * (size_t)T + (size_t)vidx) * (size_t)C + (size_t)c] > 0.0f)
      val = ev;
  }
  out[idx] = __float_as_uint(val);
}

extern "C" void kernel_launch(void* const* d_in, const int* in_sizes, int n_in,
                              void* d_out, int out_size, void* d_ws, size_t ws_size,
                              hipStream_t stream) {
  const float* q = (const float*)d_in[0];
  const float* k = (const float*)d_in[1];
  const float* v = (const float*)d_in[2];
  const float* e = (const float*)d_in[3];

  const int C = in_sizes[3];
  const int T = TLEN;
  const int B = in_sizes[0] / (T * C);
  const int total = out_size;

  samx_main<<<dim3(B * C), dim3(64), 0, stream>>>(q, k, (unsigned*)d_out, T, C);
  samx_epilogue<<<dim3((total + 255) / 256), dim3(256), 0, stream>>>(
      v, e, (unsigned*)d_out, T, C, total);
}

// Round 11
// 2198.729 us; speedup vs baseline: 7.4973x; 7.4973x over previous
//
#include <hip/hip_runtime.h>

// samx_qkv_1bit R11: lane-parallel suffix chain. Lane t OWNS chain slot t
// (cid register). R10 verified the chain-image semantics (absmax 0); R10's
// loss was wave-shared readlane/switch machinery + lane-0 serial store loops.
// Here the wave's 64 lanes do the chain work in parallel:
//   gather:    img = tk[cid]  (1 ds_read/lane, hoisted above the query walk)
//   breaker:   __ballot(img != -1) + ctz           -> t2, d
//   prefix:    lanes < t2 store tk[cid] = j        (parallel, blind)
//   clone:     broadcast loads of flml[d]/tr[d], lane-0 stores
//   redirect:  masked ballot run from t2, parallel tk[cid] = bb
//   new chain: [j] ++ dedup(images) ++ [root]; adjacent-dedup run-starts via
//              lane shuffle; compaction via 6-step bit-select + one shuffle
//   propagation: parallel predicated rl[nv] = i    (was ~12 serial levels)
// State: R7 split arrays, exactly 40960 B -> 4 blocks/CU, all 1024 rows
// co-resident. Query side: verbatim R7. Chain > 64 -> R10-verified serial
// fallback step (cold; random-data chains ~25 long).

#define NSTATES 4096
#define TLEN 2048

typedef unsigned long long u64m;

// position of the (r+1)-th set bit of mask (garbage if r<0 or r>=popc(mask))
__device__ __forceinline__ int selbit(u64m mask, int r) {
  int s = 0;
#pragma unroll
  for (int b = 32; b >= 1; b >>= 1) {
    const u64m lowmask = (s + b >= 64) ? ~0ull : ((1ull << (s + b)) - 1ull);
    if (__builtin_popcountll(mask & lowmask) <= r) s += b;
  }
  return s;
}

__global__ __launch_bounds__(64)
void samx_main(const float* __restrict__ q,
               const float* __restrict__ k,
               unsigned* __restrict__ outpos,
               int T, int C) {
  __shared__ unsigned short tr0a[NSTATES];
  __shared__ unsigned short tr1a[NSTATES];
  __shared__ unsigned       flml[NSTATES];  // fl[15:0] (0xFFFF=-1), ml[31:16]
  __shared__ unsigned short rla[NSTATES];   // last end pos, 0xFFFF = -1

  const int row = blockIdx.x;
  const int b = row / C;
  const int c = row - b * C;
  const int lane = threadIdx.x;

  for (int s = lane; s < NSTATES; s += 64) {
    tr0a[s] = 0xFFFFu; tr1a[s] = 0xFFFFu;
    flml[s] = 0x0000FFFFu; rla[s] = 0xFFFFu;
  }

  const size_t rowbase = (size_t)b * (size_t)T * (size_t)C + (size_t)c;
  const float* qr = q + rowbase;
  const float* kr = k + rowbase;
  unsigned* outr = outpos + rowbase;

  // Pre-binarize: lane L holds bits t = 32L..32L+31 of q and k.
  unsigned qw = 0u, kw = 0u;
  {
    const int t0 = lane * 32;
#pragma unroll 8
    for (int jj = 0; jj < 32; ++jj) {
      const int t = t0 + jj;
      if (qr[(size_t)t * C] > 0.0f) qw |= (1u << jj);
      if (kr[(size_t)t * C] > 0.0f) kw |= (1u << jj);
    }
  }
  __syncthreads();
  // All 64 lanes run the loop; control flow is wave-uniform.

  int cid = 0;                  // my chain slot's state id (slot = lane)
  bool cval = (lane == 0);      // slot validity (valid slots contiguous 0..len-1)
  bool trunc = false;

  int g = 0;    // last state (uniform; used by fallback)
  int mlg = 0;  // ml[g]
  int u = 1;    // next free state id
  int w = 0;    // query-match state
  int h = 0;    // query-match length

  for (int i = 0; i < T; ++i) {
    const unsigned qwi = (unsigned)__builtin_amdgcn_readlane((int)qw, i >> 5);
    const unsigned kwi = (unsigned)__builtin_amdgcn_readlane((int)kw, i >> 5);
    const int qs = (int)((qwi >> (i & 31)) & 1u);
    const int ks = (int)((kwi >> (i & 31)) & 1u);
    unsigned short* tq = qs ? tr1a : tr0a;
    unsigned short* tk = ks ? tr1a : tr0a;

    // ---- hoisted chain gather (read-only; latency hides under query) ----
    const int img = (int)(short)tk[cid];
    const unsigned fmself = flml[cid];
    const int myml = (int)(fmself >> 16);

    // ================= QUERY (verbatim R7; wave-uniform) =================
    int p = w, x = h;
    int pnew, xnew;
    for (;;) {
      if (p == -1) { pnew = 0; xnew = 0; break; }
      const int t = (int)(short)tq[p];
      const unsigned fm = flml[p];
      if (t != -1) { pnew = t; xnew = x + 1; break; }
      const int mp = (int)(fm >> 16);
      if (x > mp) x = mp;
      p = (int)(short)(fm & 0xFFFFu);
    }
    p = pnew; x = xnew;

    int vst = p;
    unsigned fmv = flml[vst];
    for (;;) {
      const int fv = (int)(short)(fmv & 0xFFFFu);
      if (fv == -1) break;
      const unsigned fmf = flml[fv];
      if ((int)(fmf >> 16) < x) break;
      vst = fv; fmv = fmf;
    }
    int rv = -1;
    for (;;) {
      if (vst == -1) { rv = -1; break; }
      const unsigned fm2 = flml[vst];
      const int r2 = (int)(short)rla[vst];
      if ((int)(fm2 >> 16) > 0 && r2 >= 0) { rv = r2; break; }
      vst = (int)(short)(fm2 & 0xFFFFu);
    }
    w = p; h = x;

    // ================= KEY SIDE =================
    const int j = u++;
    const int mlj = mlg + 1;

    if (!trunc) {
      const u64m brkmask = __ballot(cval && img != -1);
      const bool nobrk = (brkmask == 0);
      const int t2 = nobrk ? 64 : (int)__builtin_ctzll(brkmask);
      const int t2c = (t2 > 63) ? 63 : t2;

      // ---- prefix stores (parallel, blind): tk[chain[t]] = j, t < t2 ----
      if (cval && lane < t2) tk[cid] = (unsigned short)j;

      const int d = __shfl(img, t2c, 64);
      const int mlp = __shfl(myml, t2c, 64);
      int flj = 0, bb = -1;
      if (!nobrk) {
        const unsigned fmd = flml[d];  // broadcast load (post-prefix-stores)
        const int mld = (int)(fmd >> 16);
        if (mlp + 1 == mld) {
          flj = d;
        } else {
          bb = u++;  // clone of d with length mlp+1
          const int dtr0 = (int)(short)tr0a[d];  // reads AFTER prefix stores
          const int dtr1 = (int)(short)tr1a[d];  // (reference order; d may be
          if (lane == 0) {                       //  a pre-t2 chain node)
            tr0a[bb] = (unsigned short)dtr0;
            tr1a[bb] = (unsigned short)dtr1;
            // rl[bb] copy elided: bb is slot 1 of the new chain -> stamped i
            flml[bb] = (fmd & 0xFFFFu) | ((unsigned)(mlp + 1) << 16);
            flml[d]  = (fmd & 0xFFFF0000u) | (unsigned)bb;
          }
          flj = bb;
        }
      }
      if (lane == 0) {
        flml[j] = (unsigned)(flj & 0xFFFF) | ((unsigned)mlj << 16);
        outr[(size_t)i * C] = (unsigned)(rv + 1);
      }

      // ---- redirect run (clone only): contiguous img==d from t2 -> bb ----
      int imgm = img;
      if (bb >= 0) {
        const u64m eq = __ballot(cval && img == d) >> t2;
        const int runlen = (eq == ~0ull) ? 64 : (int)__builtin_ctzll(~eq);
        const bool inrun = cval && lane >= t2 && lane < t2 + runlen;
        if (inrun) { imgm = bb; tk[cid] = (unsigned short)bb; }
      }

      // ---- dedup run-starts (duplicates are adjacent: path projection) ----
      int lm1 = lane - 1; if (lm1 < 0) lm1 = 0;
      const int previmg = __shfl(imgm, lm1, 64);
      const bool rs = cval && lane >= t2 && (lane == t2 || imgm != previmg);
      const u64m rsmask = __ballot(rs);
      const int ndd = (int)__builtin_popcountll(rsmask);
      const int newlen = ndd + 2;  // [j] + ndd images + [root]

      // ---- build new chain: slot r<-(r-1)-th run-start's image ----
      const int r = lane - 1;
      int rcl = r; if (rcl < 0) rcl = 0; if (rcl > 63) rcl = 63;
      int srcc = selbit(rsmask, rcl); if (srcc > 63) srcc = 63;
      const int imgsel = __shfl(imgm, srcc, 64);
      int nv = 0;  // default root/padding (safe gather next step)
      if (lane == 0) nv = j;
      else if (r < ndd) nv = imgsel;
      const bool nval = (lane < newlen);

      // ---- propagation: parallel blind stamps of the whole new chain ----
      if (nval) rla[nv] = (unsigned short)i;

      const bool overflow = (newlen > 64);
      if (overflow) {  // cold: stamp the unstored tail serially
        const int nv63 = __shfl(nv, 63, 64);
        if (lane == 0) {
          int vp = (int)(short)(flml[nv63] & 0xFFFFu);
          while (vp != -1) {
            rla[vp] = (unsigned short)i;
            vp = (int)(short)(flml[vp] & 0xFFFFu);
          }
        }
      }
      cid = nv; cval = nval && !overflow ? nval : (nval && lane < 64);
      cval = nval;
      trunc = overflow;
    } else {
      // ======= COLD fallback: reference-exact serial step (R10-verified) ====
      int pcur = g, d2 = -1, idbrk = -1;
      for (;;) {
        if (pcur == -1) break;
        const int tv = (int)(short)tk[pcur];
        const unsigned fm = flml[pcur];
        if (tv != -1) { d2 = tv; idbrk = pcur; break; }
        if (lane == 0) tk[pcur] = (unsigned short)j;
        pcur = (int)(short)(fm & 0xFFFFu);
      }
      int flj = 0;
      if (d2 != -1) {
        const int mlp = (int)(flml[idbrk] >> 16);
        const unsigned fmd = flml[d2];
        const int mld = (int)(fmd >> 16);
        if (mlp + 1 == mld) {
          flj = d2;
        } else {
          const int bb = u++;
          const int dtr0 = (int)(short)tr0a[d2];
          const int dtr1 = (int)(short)tr1a[d2];
          const int drl  = (int)(short)rla[d2];
          if (lane == 0) {
            tr0a[bb] = (unsigned short)dtr0;
            tr1a[bb] = (unsigned short)dtr1;
            rla[bb]  = (unsigned short)drl;
            flml[bb] = (fmd & 0xFFFFu) | ((unsigned)(mlp + 1) << 16);
            flml[d2] = (fmd & 0xFFFF0000u) | (unsigned)bb;
          }
          flj = bb;
          int p3 = idbrk;
          for (;;) {
            if (p3 == -1) break;
            const int tv3 = (int)(short)tk[p3];
            const unsigned fm3 = flml[p3];
            if (tv3 != d2) break;
            if (lane == 0) tk[p3] = (unsigned short)bb;
            p3 = (int)(short)(fm3 & 0xFFFFu);
          }
        }
      }
      if (lane == 0) {
        flml[j] = (unsigned)(flj & 0xFFFF) | ((unsigned)mlj << 16);
        outr[(size_t)i * C] = (unsigned)(rv + 1);
      }
      // full propagation walk; rebuild lane chain while stamping
      int vp = j, ncs = 0;
      bool tr2 = false;
      for (;;) {
        if (vp == -1) break;
        if (ncs < 64) { if (lane == ncs) cid = vp; ++ncs; }
        else tr2 = true;
        if (lane == 0) rla[vp] = (unsigned short)i;
        vp = (int)(short)(flml[vp] & 0xFFFFu);
      }
      cval = (lane < ncs);
      trunc = tr2;
    }
    g = j; mlg = mlj;
  }
}

// Fully parallel epilogue: vidx (u32, = r+1, 0 = no match) -> sign*e.
__global__ __launch_bounds__(256)
void samx_epilogue(const float* __restrict__ v,
                   const float* __restrict__ e,
                   unsigned* __restrict__ out,
                   int T, int C, int total) {
  const int idx = blockIdx.x * 256 + threadIdx.x;
  if (idx >= total) return;
  const unsigned vidx = out[idx];
  const int c = idx % C;
  const int bi = idx / C;
  const int b = bi / T;
  const float ev = e[c];
  float val = -ev;  // y=0
  if (vidx != 0u) {
    if (v[((size_t)b * (size_t)T + (size_t)vidx) * (size_t)C + (size_t)c] > 0.0f)
      val = ev;
  }
  out[idx] = __float_as_uint(val);
}

extern "C" void kernel_launch(void* const* d_in, const int* in_sizes, int n_in,
                              void* d_out, int out_size, void* d_ws, size_t ws_size,
                              hipStream_t stream) {
  const float* q = (const float*)d_in[0];
  const float* k = (const float*)d_in[1];
  const float* v = (const float*)d_in[2];
  const float* e = (const float*)d_in[3];

  const int C = in_sizes[3];
  const int T = TLEN;
  const int B = in_sizes[0] / (T * C);
  const int total = out_size;

  samx_main<<<dim3(B * C), dim3(64), 0, stream>>>(q, k, (unsigned*)d_out, T, C);
  samx_epilogue<<<dim3((total + 255) / 256), dim3(256), 0, stream>>>(
      v, e, (unsigned*)d_out, T, C, total);
}